// Round 5
// baseline (1432.134 us; speedup 1.0000x reference)
//
#include <hip/hip_runtime.h>

// Residual VQ forward: x [B=16, D=256, T=4096] fp32, codebooks [NQ=8, BINS=1024, D=256] fp32.
// d_out = quantized [B,D,T] fp32 ++ codes [NQ,B,T] as float.
// Round 5: software-pipelined fold (MFMA || prev-chunk top-2), leaner fold, full fp64
// rescan on near-tie, m-inner final store.

#define BB   16
#define DD   256
#define TT   4096
#define NQ   8
#define BINS 1024
#define DELTA 0.0078125f
#define OUTQ ((size_t)BB * DD * TT)

typedef __attribute__((ext_vector_type(8))) short bfrag;
typedef __attribute__((ext_vector_type(8))) unsigned short ushort8;
typedef __attribute__((ext_vector_type(4))) float facc;

__device__ inline float bfh2f(unsigned short h) {
    union { unsigned u; float f; } cv; cv.u = ((unsigned)h) << 16; return cv.f;
}
__device__ inline unsigned short f2bf(float f) {
    union { float f; unsigned u; } cv; cv.f = f;
    unsigned r = cv.u + 0x7fff + ((cv.u >> 16) & 1);
    return (unsigned short)(r >> 16);
}

#define MFMA(A, B, C) __builtin_amdgcn_mfma_f32_16x16x32_bf16((A), (B), (C), 0, 0, 0)

// ---------- pack kernel: fp32 codebook -> pre-swizzled hi/lo bf16 planes ----------
__global__ __launch_bounds__(256)
void rvq_pack_swz(const float* __restrict__ cb, unsigned short* __restrict__ pks) {
    int gid = blockIdx.x * 256 + threadIdx.x;       // (q, bin, s)
    int s   = gid & 7;
    int bin = (gid >> 3) & 1023;
    int q   = gid >> 13;
    const float* src = cb + ((size_t)(q * BINS + bin)) * DD + s * 32;
    int cc    = q * 32 + (bin >> 5);
    int nf    = (bin >> 4) & 1;
    int c     = bin & 15;
    int plane = nf * 8 + s;
    size_t base = (size_t)cc * 16384 + (size_t)plane * 512 + c * 8;   // short units
    #pragma unroll
    for (int g = 0; g < 4; ++g) {
        float4 v0 = *(const float4*)(src + g * 8);
        float4 v1 = *(const float4*)(src + g * 8 + 4);
        float vv[8] = { v0.x, v0.y, v0.z, v0.w, v1.x, v1.y, v1.z, v1.w };
        ushort8 h8, l8;
        #pragma unroll
        for (int j = 0; j < 8; ++j) {
            unsigned short h = f2bf(vv[j]);
            h8[j] = h;
            l8[j] = f2bf(vv[j] - bfh2f(h));
        }
        *(ushort8*)&pks[base + g * 128]        = h8;   // term 0 (hi)
        *(ushort8*)&pks[base + 8192 + g * 128] = l8;   // term 1 (lo)
    }
}

__global__ __launch_bounds__(256)
void rvq_esq_half(const float* __restrict__ cb, float* __restrict__ hesq) {
    int q = blockIdx.x;
    const float* e = cb + (size_t)q * BINS * DD;
    for (int bin = threadIdx.x; bin < BINS; bin += 256) {
        const float4* row = (const float4*)(e + (size_t)bin * DD);
        float s = 0.f;
        #pragma unroll 8
        for (int i = 0; i < DD / 4; ++i) {
            float4 v = row[i];
            s += v.x * v.x + v.y * v.y + v.z * v.z + v.w * v.w;
        }
        hesq[q * BINS + bin] = 0.5f * s;
    }
}

// CHUNK_BODY: 96 MFMAs of chunk in buffer BU into CUR; if DOFOLD, interleave the
// top-2 fold of PRV (previous chunk's scores) one slot per k-slice group.
#define CHUNK_BODY(BU, CUR, PRV, DOFOLD, Q0P, Q1P, BIN0P) do {               \
    _Pragma("unroll")                                                        \
    for (int _m = 0; _m < 2; ++_m)                                           \
        _Pragma("unroll")                                                    \
        for (int _n = 0; _n < 2; ++_n)                                       \
            CUR[_m][_n] = (facc){0.f, 0.f, 0.f, 0.f};                        \
    const int _roff = g * 128 + c * 8;                                       \
    __builtin_amdgcn_s_setprio(1);                                           \
    _Pragma("unroll")                                                        \
    for (int _s = 0; _s < 8; ++_s) {                                         \
        bfrag _bh0 = *(const bfrag*)&btile[BU][0][_s][_roff];                \
        bfrag _bh1 = *(const bfrag*)&btile[BU][0][8 + _s][_roff];            \
        bfrag _bl0 = *(const bfrag*)&btile[BU][1][_s][_roff];                \
        bfrag _bl1 = *(const bfrag*)&btile[BU][1][8 + _s][_roff];            \
        CUR[0][0] = MFMA(ah[0][_s], _bh0, CUR[0][0]);                        \
        CUR[1][0] = MFMA(ah[1][_s], _bh0, CUR[1][0]);                        \
        CUR[0][1] = MFMA(ah[0][_s], _bh1, CUR[0][1]);                        \
        CUR[1][1] = MFMA(ah[1][_s], _bh1, CUR[1][1]);                        \
        CUR[0][0] = MFMA(al[0][_s], _bh0, CUR[0][0]);                        \
        CUR[1][0] = MFMA(al[1][_s], _bh0, CUR[1][0]);                        \
        CUR[0][1] = MFMA(al[0][_s], _bh1, CUR[0][1]);                        \
        CUR[1][1] = MFMA(al[1][_s], _bh1, CUR[1][1]);                        \
        CUR[0][0] = MFMA(ah[0][_s], _bl0, CUR[0][0]);                        \
        CUR[1][0] = MFMA(ah[1][_s], _bl0, CUR[1][0]);                        \
        CUR[0][1] = MFMA(ah[0][_s], _bl1, CUR[0][1]);                        \
        CUR[1][1] = MFMA(ah[1][_s], _bl1, CUR[1][1]);                        \
        if (DOFOLD) {                                                        \
            const int _fm = _s >> 2, _fj = _s & 3;                           \
            float _v0 = PRV[_fm][0][_fj] - (Q0P);                            \
            float _v1 = PRV[_fm][1][_fj] - (Q1P);                            \
            bool  _fi = _v0 >= _v1;                                          \
            float _hi = _fi ? _v0 : _v1;                                     \
            float _lo = _fi ? _v1 : _v0;                                     \
            int   _ih = _fi ? (BIN0P) : (BIN0P) + 16;                        \
            bool  _gt = _hi > fs1[_fm][_fj];                                 \
            float _t1 = _gt ? fs1[_fm][_fj] : fs2[_fm][_fj];                 \
            float _t2 = _gt ? _lo : _hi;                                     \
            fs2[_fm][_fj] = fmaxf(_t1, _t2);                                 \
            fi1[_fm][_fj] = _gt ? _ih : fi1[_fm][_fj];                       \
            fs1[_fm][_fj] = fmaxf(_hi, fs1[_fm][_fj]);                       \
        }                                                                    \
    }                                                                        \
    __builtin_amdgcn_s_setprio(0);                                           \
} while (0)

// ---------- main MFMA kernel: 512 blocks x 256 thr (4 waves), 128 tokens/block ----------
__global__ __launch_bounds__(256, 2)
void rvq_mfma3_kernel(const float* __restrict__ x, const float* __restrict__ cb,
                      const unsigned short* __restrict__ pks, const float* __restrict__ hesq,
                      float* __restrict__ out)
{
    __shared__ alignas(16) short btile[2][2][16][512];   // 64 KB double-buffered chunk
    __shared__ float refine_lds[4][256];                 // per-wave exact residual row
    __shared__ unsigned short best_lds[4][32];
    __shared__ unsigned short hist_lds[4][NQ][32];

    const int tid = threadIdx.x;
    const int w   = tid >> 6;
    const int l   = tid & 63;
    const int c   = l & 15;
    const int g   = l >> 4;

    const int blk = blockIdx.x;        // 512 blocks
    const int b   = blk >> 5;          // 32 blocks per batch element
    const int t0  = (blk & 31) * 128;
    const int tw  = t0 + w * 32;

    const char* gsrc0 = (const char*)pks + w * 8192 + (l << 4);

    auto issue_chunk = [&](int cc, int bu) {
        cc &= 255;
        const char* src = gsrc0 + (size_t)cc * 32768;
        char* dst = (char*)(&btile[bu][0][0][0]) + w * 8192;
        #pragma unroll
        for (int i = 0; i < 8; ++i) {
            __builtin_amdgcn_global_load_lds(
                (const __attribute__((address_space(1))) unsigned int*)(src + i * 1024),
                (__attribute__((address_space(3))) unsigned int*)(dst + i * 1024),
                16, 0, 0);
        }
    };

    issue_chunk(0, 0);   // prefetch chunk 0 under the A-init loads

    // ---- A init: residual = x, split to hi/lo MFMA fragments ----
    bfrag ah[2][8], al[2][8];
    {
        const float* xb = x + (size_t)b * DD * TT;
        #pragma unroll
        for (int s = 0; s < 8; ++s) {
            #pragma unroll
            for (int j = 0; j < 8; ++j) {
                int d = s * 32 + g * 8 + j;
                #pragma unroll
                for (int m = 0; m < 2; ++m) {
                    int t = tw + m * 16 + c;
                    float v = xb[(size_t)d * TT + t];
                    unsigned short h = f2bf(v);
                    float rem = v - bfh2f(h);
                    ah[m][s][j] = (short)h;
                    al[m][s][j] = (short)f2bf(rem);
                }
            }
        }
    }
    __syncthreads();   // drains vmcnt -> chunk 0 resident

    // fold state: slot (fm, fj) = token fm*16 + 4*g + fj
    float fs1[2][4], fs2[2][4];
    int   fi1[2][4];
    facc accP[2][2], accQ[2][2];

    // exact fp64 rescan over all 1024 bins (rare near-tie path)
    auto refine = [&](int tkl, int qq) -> int {
        int t = tw + tkl;
        float rv[4];
        #pragma unroll
        for (int dd = 0; dd < 4; ++dd) {
            int d = l * 4 + dd;
            float r = x[((size_t)b * DD + d) * TT + t];
            for (int k = 0; k < qq; ++k) {
                int hb = hist_lds[w][k][tkl];
                r -= cb[(size_t)(k * BINS + hb) * DD + d];
            }
            rv[dd] = r;
        }
        *(float4*)&refine_lds[w][l * 4] = *(float4*)rv;
        asm volatile("s_waitcnt lgkmcnt(0)" ::: "memory");
        double bs = -1e300; int bbin = 0;
        for (int k2 = 0; k2 < 16; ++k2) {
            int bin = k2 * 64 + l;
            const float* ep = cb + (size_t)(qq * BINS + bin) * DD;
            double acc = 0.0;
            for (int d = 0; d < DD; d += 4) {
                float4 e4 = *(const float4*)(ep + d);
                float r0 = refine_lds[w][d],     r1 = refine_lds[w][d + 1];
                float r2 = refine_lds[w][d + 2], r3 = refine_lds[w][d + 3];
                acc += (double)e4.x * (2.0 * (double)r0 - (double)e4.x);
                acc += (double)e4.y * (2.0 * (double)r1 - (double)e4.y);
                acc += (double)e4.z * (2.0 * (double)r2 - (double)e4.z);
                acc += (double)e4.w * (2.0 * (double)r3 - (double)e4.w);
            }
            if (acc > bs) { bs = acc; bbin = bin; }   // bins increase within lane
        }
        #pragma unroll
        for (int mk = 1; mk < 64; mk <<= 1) {
            double ob  = __shfl_xor(bs, mk);
            int  obin  = __shfl_xor(bbin, mk);
            if (ob > bs || (ob == bs && obin < bbin)) { bs = ob; bbin = obin; }
        }
        return bbin;
    };

    auto stage_end = [&](int qq) {
        int  bch[2][4];
        bool gate[2][4];
        #pragma unroll
        for (int fm = 0; fm < 2; ++fm) {
            #pragma unroll
            for (int fj = 0; fj < 4; ++fj) {
                float a1 = fs1[fm][fj], a2 = fs2[fm][fj];
                int   x1 = fi1[fm][fj];
                #pragma unroll
                for (int mk = 1; mk < 16; mk <<= 1) {
                    float b1 = __shfl_xor(a1, mk);
                    float b2 = __shfl_xor(a2, mk);
                    int   y1 = __shfl_xor(x1, mk);
                    bool pk = (b1 > a1) || (b1 == a1 && y1 < x1);
                    float lose = pk ? a1 : b1;
                    a2 = fmaxf(fmaxf(a2, b2), lose);
                    a1 = pk ? b1 : a1;
                    x1 = pk ? y1 : x1;
                }
                bch[fm][fj]  = x1;
                gate[fm][fj] = (a1 - a2 <= DELTA);
            }
        }
        bool anyg = gate[0][0] | gate[0][1] | gate[0][2] | gate[0][3]
                  | gate[1][0] | gate[1][1] | gate[1][2] | gate[1][3];
        if (__any(anyg)) {
            #pragma unroll
            for (int fm = 0; fm < 2; ++fm) {
                #pragma unroll
                for (int fj = 0; fj < 4; ++fj) {
                    unsigned long long nm = __ballot(gate[fm][fj]);
                    if (nm) {
                        for (int g2 = 0; g2 < 4; ++g2) {
                            if ((nm >> (g2 * 16)) & 1ull) {
                                int tkl = fm * 16 + g2 * 4 + fj;
                                int wb = refine(tkl, qq);
                                if (g == g2) bch[fm][fj] = wb;
                            }
                        }
                    }
                }
            }
        }

        if (c == 0) {
            #pragma unroll
            for (int fm = 0; fm < 2; ++fm)
                #pragma unroll
                for (int fj = 0; fj < 4; ++fj) {
                    int tkl = fm * 16 + g * 4 + fj;
                    best_lds[w][tkl] = (unsigned short)bch[fm][fj];
                    hist_lds[w][qq][tkl] = (unsigned short)bch[fm][fj];
                    out[OUTQ + ((size_t)qq * BB + b) * TT + tw + tkl] = (float)bch[fm][fj];
                }
        }

        // residual update from EXACT fp32 codebook row: r -= e[best], re-split hi/lo
        #pragma unroll
        for (int m = 0; m < 2; ++m) {
            int bin = best_lds[w][m * 16 + c];
            const float* ep = cb + (size_t)(qq * BINS + bin) * DD + g * 8;
            #pragma unroll
            for (int s = 0; s < 8; ++s) {
                float4 e0 = *(const float4*)(ep + s * 32);
                float4 e1 = *(const float4*)(ep + s * 32 + 4);
                float ev[8] = { e0.x, e0.y, e0.z, e0.w, e1.x, e1.y, e1.z, e1.w };
                #pragma unroll
                for (int j = 0; j < 8; ++j) {
                    float rv = bfh2f((unsigned short)ah[m][s][j]) + bfh2f((unsigned short)al[m][s][j]);
                    float nr = rv - ev[j];
                    unsigned short nh = f2bf(nr);
                    float rem = nr - bfh2f(nh);
                    ah[m][s][j] = (short)nh;
                    al[m][s][j] = (short)f2bf(rem);
                }
            }
        }
    };

    // ---- main loop: 8 stages x 32 chunks; fold pipelined one chunk behind ----
    int buf = 0;
    #pragma unroll 1
    for (int q = 0; q < NQ; ++q) {
        #pragma unroll
        for (int fm = 0; fm < 2; ++fm)
            #pragma unroll
            for (int fj = 0; fj < 4; ++fj) {
                fs1[fm][fj] = -1e30f; fs2[fm][fj] = -1e30f; fi1[fm][fj] = 0;
            }
        const int base = q * 32;
        const float* hqs = hesq + q * BINS;
        float q0p, q1p; int bin0p;
        {   // peel chunk 0 (no fold)
            issue_chunk(base + 1, buf ^ 1);
            float nq0 = hqs[c], nq1 = hqs[16 + c];
            CHUNK_BODY(buf, accP, accP, 0, 0.f, 0.f, 0);
            q0p = nq0; q1p = nq1; bin0p = c;
            __syncthreads(); buf ^= 1;
        }
        #pragma unroll 1
        for (int pr = 0; pr < 15; ++pr) {
            {
                const int ch = 1 + 2 * pr;
                issue_chunk(base + ch + 1, buf ^ 1);
                float nq0 = hqs[ch * 32 + c], nq1 = hqs[ch * 32 + 16 + c];
                CHUNK_BODY(buf, accQ, accP, 1, q0p, q1p, bin0p);
                q0p = nq0; q1p = nq1; bin0p = ch * 32 + c;
                __syncthreads(); buf ^= 1;
            }
            {
                const int ch = 2 + 2 * pr;
                issue_chunk(base + ch + 1, buf ^ 1);
                float nq0 = hqs[ch * 32 + c], nq1 = hqs[ch * 32 + 16 + c];
                CHUNK_BODY(buf, accP, accQ, 1, q0p, q1p, bin0p);
                q0p = nq0; q1p = nq1; bin0p = ch * 32 + c;
                __syncthreads(); buf ^= 1;
            }
        }
        {   // chunk 31
            issue_chunk(base + 32, buf ^ 1);   // next stage's chunk 0 (wraps at q=7)
            float nq0 = hqs[31 * 32 + c], nq1 = hqs[31 * 32 + 16 + c];
            CHUNK_BODY(buf, accQ, accP, 1, q0p, q1p, bin0p);
            q0p = nq0; q1p = nq1; bin0p = 31 * 32 + c;
            __syncthreads(); buf ^= 1;
        }
        // epilogue: fold chunk 31 (accQ)
        #pragma unroll
        for (int ss = 0; ss < 8; ++ss) {
            const int fm = ss >> 2, fj = ss & 3;
            float v0 = accQ[fm][0][fj] - q0p;
            float v1 = accQ[fm][1][fj] - q1p;
            bool  fi = v0 >= v1;
            float hi = fi ? v0 : v1;
            float lo = fi ? v1 : v0;
            int   ih = fi ? bin0p : bin0p + 16;
            bool  gt = hi > fs1[fm][fj];
            float t1 = gt ? fs1[fm][fj] : fs2[fm][fj];
            float t2 = gt ? lo : hi;
            fs2[fm][fj] = fmaxf(t1, t2);
            fi1[fm][fj] = gt ? ih : fi1[fm][fj];
            fs1[fm][fj] = fmaxf(hi, fs1[fm][fj]);
        }
        stage_end(q);
    }

    // ---- final: quantized = x - residual (m-inner: full 128B line back-to-back) ----
    {
        const float* xb = x + (size_t)b * DD * TT;
        float* ob = out + (size_t)b * DD * TT;
        #pragma unroll
        for (int s = 0; s < 8; ++s)
            #pragma unroll
            for (int j = 0; j < 8; ++j) {
                int d = s * 32 + g * 8 + j;
                #pragma unroll
                for (int m = 0; m < 2; ++m) {
                    int t = tw + m * 16 + c;
                    float rv = bfh2f((unsigned short)ah[m][s][j]) + bfh2f((unsigned short)al[m][s][j]);
                    ob[(size_t)d * TT + t] = xb[(size_t)d * TT + t] - rv;
                }
            }
    }
}

// ================= fallback fp32 path (round-2, known-good) =================
#define TOK_PER_BLK 32
#define BIN_CHUNK   128
#define KC          32
#define EPAD        36
#define RPAD        260

#define FUPD2(S, BIN, B1, I1, B2, I2)                                        \
    if ((S) > (B2) || ((S) == (B2) && (BIN) < (I2))) {                      \
        if ((S) > (B1) || ((S) == (B1) && (BIN) < (I1))) {                  \
            B2 = B1; I2 = I1; B1 = (S); I1 = (BIN);                         \
        } else { B2 = (S); I2 = (BIN); }                                    \
    }

__global__ __launch_bounds__(256, 2)
void rvq_esq_kernel(const float* __restrict__ cb, float* __restrict__ esq) {
    int q = blockIdx.x;
    const float* e = cb + (size_t)q * BINS * DD;
    for (int bin = threadIdx.x; bin < BINS; bin += 256) {
        const float4* row = (const float4*)(e + (size_t)bin * DD);
        float s = 0.f;
        #pragma unroll 8
        for (int i = 0; i < DD / 4; ++i) {
            float4 v = row[i];
            s += v.x * v.x + v.y * v.y + v.z * v.z + v.w * v.w;
        }
        esq[q * BINS + bin] = s;
    }
}

__global__ __launch_bounds__(256, 2)
void rvq_main_kernel(const float* __restrict__ x, const float* __restrict__ cb,
                     const float* __restrict__ esq, float* __restrict__ out) {
    __shared__ float r_lds[TOK_PER_BLK][RPAD];
    __shared__ float e_lds[BIN_CHUNK][EPAD];
    __shared__ float red_s[16][2][TOK_PER_BLK];
    __shared__ int   red_i[16][2][TOK_PER_BLK];
    __shared__ int   best_lds2[TOK_PER_BLK];

    const int tid = threadIdx.x;
    const int blk = blockIdx.x;
    const int b   = blk >> 7;
    const int t0  = (blk & 127) * TOK_PER_BLK;

    {
        const int tl = tid & 31;
        const int d0 = (tid >> 5) * 32;
        const float* xp = x + (size_t)b * DD * TT + t0 + tl;
        for (int dd = 0; dd < 32; ++dd) {
            int d = d0 + dd;
            r_lds[tl][d] = xp[(size_t)d * TT];
        }
    }
    __syncthreads();

    const int ty = tid >> 4;
    const int tx = tid & 15;

    for (int q = 0; q < NQ; ++q) {
        const float* eb = cb + (size_t)q * BINS * DD;
        const float* es = esq + q * BINS;
        float b1[2] = {-1e30f, -1e30f}, b2[2] = {-1e30f, -1e30f};
        int   i1[2] = {0x7fffffff, 0x7fffffff}, i2[2] = {0x7fffffff, 0x7fffffff};

        for (int cch = 0; cch < BINS / BIN_CHUNK; ++cch) {
            float acc[2][8];
            #pragma unroll
            for (int i = 0; i < 2; ++i)
                #pragma unroll
                for (int j = 0; j < 8; ++j) acc[i][j] = 0.f;

            for (int kc = 0; kc < DD / KC; ++kc) {
                __syncthreads();
                {
                    const int col  = tid & 7;
                    const int row0 = tid >> 3;
                    const float* src = eb + (size_t)(cch * BIN_CHUNK) * DD + kc * KC;
                    #pragma unroll
                    for (int rr = 0; rr < 4; ++rr) {
                        int row = row0 + rr * 32;
                        float4 v = *(const float4*)(src + (size_t)row * DD + col * 4);
                        *(float4*)&e_lds[row][col * 4] = v;
                    }
                }
                __syncthreads();
                #pragma unroll
                for (int k4 = 0; k4 < KC / 4; ++k4) {
                    float4 r0 = *(const float4*)&r_lds[tx][kc * KC + k4 * 4];
                    float4 r1 = *(const float4*)&r_lds[tx + 16][kc * KC + k4 * 4];
                    #pragma unroll
                    for (int bi = 0; bi < 8; ++bi) {
                        float4 e4 = *(const float4*)&e_lds[ty + 16 * bi][k4 * 4];
                        acc[0][bi] += r0.x * e4.x + r0.y * e4.y + r0.z * e4.z + r0.w * e4.w;
                        acc[1][bi] += r1.x * e4.x + r1.y * e4.y + r1.z * e4.z + r1.w * e4.w;
                    }
                }
            }
            #pragma unroll
            for (int bi = 0; bi < 8; ++bi) {
                int bin = cch * BIN_CHUNK + ty + 16 * bi;
                float half_esq = 0.5f * es[bin];
                float s0 = acc[0][bi] - half_esq;
                float s1v = acc[1][bi] - half_esq;
                FUPD2(s0, bin, b1[0], i1[0], b2[0], i2[0]);
                FUPD2(s1v, bin, b1[1], i1[1], b2[1], i2[1]);
            }
        }

        #pragma unroll
        for (int k = 0; k < 2; ++k) {
            red_s[ty][k][tx]      = k ? b2[0] : b1[0];
            red_i[ty][k][tx]      = k ? i2[0] : i1[0];
            red_s[ty][k][tx + 16] = k ? b2[1] : b1[1];
            red_i[ty][k][tx + 16] = k ? i2[1] : i1[1];
        }
        __syncthreads();

        if (tid < TOK_PER_BLK) {
            float g1 = -1e30f, g2 = -1e30f; int gi1 = 0x7fffffff, gi2 = 0x7fffffff;
            #pragma unroll
            for (int j = 0; j < 16; ++j) {
                #pragma unroll
                for (int k = 0; k < 2; ++k) {
                    float s = red_s[j][k][tid]; int ii = red_i[j][k][tid];
                    FUPD2(s, ii, g1, gi1, g2, gi2);
                }
            }
            int bif;
            if (g1 - g2 <= DELTA) {
                const float* rrow = r_lds[tid];
                double sc[2]; int id2[2] = { gi1, gi2 };
                for (int cc2 = 0; cc2 < 2; ++cc2) {
                    const float* ep = eb + (size_t)id2[cc2] * DD;
                    double acc2 = 0.0;
                    #pragma unroll 4
                    for (int d = 0; d < DD; ++d) {
                        double ev = (double)ep[d];
                        acc2 += ev * (2.0 * (double)rrow[d] - ev);
                    }
                    sc[cc2] = acc2;
                }
                bif = (sc[0] > sc[1] || (sc[0] == sc[1] && id2[0] < id2[1])) ? id2[0] : id2[1];
            } else {
                bif = gi1;
            }
            best_lds2[tid] = bif;
            out[OUTQ + (size_t)q * (BB * TT) + (size_t)b * TT + t0 + tid] = (float)bif;
        }
        __syncthreads();

        {
            const int tok  = tid >> 3;
            const int part = tid & 7;
            const int bin  = best_lds2[tok];
            const float* ep = eb + (size_t)bin * DD + part * 32;
            float* rp = &r_lds[tok][part * 32];
            #pragma unroll
            for (int dd = 0; dd < 32; ++dd) rp[dd] -= ep[dd];
        }
        __syncthreads();
    }

    {
        const int tl = tid & 31;
        const int d0 = (tid >> 5) * 32;
        const float* xp = x + (size_t)b * DD * TT + t0 + tl;
        float*       op = out + (size_t)b * DD * TT + t0 + tl;
        for (int dd = 0; dd < 32; ++dd) {
            int d = d0 + dd;
            op[(size_t)d * TT] = xp[(size_t)d * TT] - r_lds[tl][d];
        }
    }
}

extern "C" void kernel_launch(void* const* d_in, const int* in_sizes, int n_in,
                              void* d_out, int out_size, void* d_ws, size_t ws_size,
                              hipStream_t stream) {
    const float* x  = (const float*)d_in[0];
    const float* cb = (const float*)d_in[1];
    float* out = (float*)d_out;

    const size_t PKS_BYTES = (size_t)NQ * BINS * DD * 2 * 2;   // 8 MB pre-swizzled hi/lo
    const size_t NEED = PKS_BYTES + (size_t)NQ * BINS * 4;     // + half-esq

    if (ws_size >= NEED) {
        unsigned short* pks = (unsigned short*)d_ws;
        float* hesq = (float*)((char*)d_ws + PKS_BYTES);
        rvq_pack_swz<<<(NQ * BINS * 8) / 256, 256, 0, stream>>>(cb, pks);
        rvq_esq_half<<<NQ, 256, 0, stream>>>(cb, hesq);
        rvq_mfma3_kernel<<<512, 256, 0, stream>>>(x, cb, pks, hesq, out);
    } else {
        float* esq = (float*)d_ws;
        rvq_esq_kernel<<<NQ, 256, 0, stream>>>(cb, esq);
        rvq_main_kernel<<<(BB * TT) / TOK_PER_BLK, 256, 0, stream>>>(x, cb, esq, out);
    }
}

// Round 6
// 807.466 us; speedup vs baseline: 1.7736x; 1.7736x over previous
//
#include <hip/hip_runtime.h>

// Residual VQ forward: x [B=16, D=256, T=4096] fp32, codebooks [NQ=8, BINS=1024, D=256] fp32.
// d_out = quantized [B,D,T] fp32 ++ codes [NQ,B,T] as float.
// Round 6: round-4 structure (no acc ping-pong) + slice-pipelined ds_reads inside
// compute_chunk (LDS pipe || matrix pipe) + m-inner init/store (128B-line locality).

#define BB   16
#define DD   256
#define TT   4096
#define NQ   8
#define BINS 1024
#define DELTA 0.0078125f
#define OUTQ ((size_t)BB * DD * TT)

typedef __attribute__((ext_vector_type(8))) short bfrag;
typedef __attribute__((ext_vector_type(8))) unsigned short ushort8;
typedef __attribute__((ext_vector_type(4))) float facc;

__device__ inline float bfh2f(unsigned short h) {
    union { unsigned u; float f; } cv; cv.u = ((unsigned)h) << 16; return cv.f;
}
__device__ inline unsigned short f2bf(float f) {
    union { float f; unsigned u; } cv; cv.f = f;
    unsigned r = cv.u + 0x7fff + ((cv.u >> 16) & 1);
    return (unsigned short)(r >> 16);
}

#define MFMA(A, B, C) __builtin_amdgcn_mfma_f32_16x16x32_bf16((A), (B), (C), 0, 0, 0)

#define UPD2(S, BIN, S1, I1, S2, I2) { \
    bool _g1 = (S) > (S1); \
    bool _g2 = (S) > (S2); \
    S2 = _g1 ? (S1) : (_g2 ? (S) : (S2)); \
    I2 = _g1 ? (I1) : (_g2 ? (BIN) : (I2)); \
    S1 = _g1 ? (S) : (S1); \
    I1 = _g1 ? (BIN) : (I1); }

// ---------- pack kernel: fp32 codebook -> pre-swizzled hi/lo bf16 planes ----------
__global__ __launch_bounds__(256)
void rvq_pack_swz(const float* __restrict__ cb, unsigned short* __restrict__ pks) {
    int gid = blockIdx.x * 256 + threadIdx.x;       // (q, bin, s)
    int s   = gid & 7;
    int bin = (gid >> 3) & 1023;
    int q   = gid >> 13;
    const float* src = cb + ((size_t)(q * BINS + bin)) * DD + s * 32;
    int cc    = q * 32 + (bin >> 5);
    int nf    = (bin >> 4) & 1;
    int c     = bin & 15;
    int plane = nf * 8 + s;
    size_t base = (size_t)cc * 16384 + (size_t)plane * 512 + c * 8;   // short units
    #pragma unroll
    for (int g = 0; g < 4; ++g) {
        float4 v0 = *(const float4*)(src + g * 8);
        float4 v1 = *(const float4*)(src + g * 8 + 4);
        float vv[8] = { v0.x, v0.y, v0.z, v0.w, v1.x, v1.y, v1.z, v1.w };
        ushort8 h8, l8;
        #pragma unroll
        for (int j = 0; j < 8; ++j) {
            unsigned short h = f2bf(vv[j]);
            h8[j] = h;
            l8[j] = f2bf(vv[j] - bfh2f(h));
        }
        *(ushort8*)&pks[base + g * 128]        = h8;   // term 0 (hi)
        *(ushort8*)&pks[base + 8192 + g * 128] = l8;   // term 1 (lo)
    }
}

__global__ __launch_bounds__(256)
void rvq_esq_half(const float* __restrict__ cb, float* __restrict__ hesq) {
    int q = blockIdx.x;
    const float* e = cb + (size_t)q * BINS * DD;
    for (int bin = threadIdx.x; bin < BINS; bin += 256) {
        const float4* row = (const float4*)(e + (size_t)bin * DD);
        float s = 0.f;
        #pragma unroll 8
        for (int i = 0; i < DD / 4; ++i) {
            float4 v = row[i];
            s += v.x * v.x + v.y * v.y + v.z * v.z + v.w * v.w;
        }
        hesq[q * BINS + bin] = 0.5f * s;
    }
}

// ---------- main MFMA kernel: 512 blocks x 256 thr (4 waves), 128 tokens/block ----------
__global__ __launch_bounds__(256, 2)
void rvq_mfma2_kernel(const float* __restrict__ x, const float* __restrict__ cb,
                      const unsigned short* __restrict__ pks, const float* __restrict__ hesq,
                      float* __restrict__ out)
{
    __shared__ alignas(16) short btile[2][2][16][512];   // 64 KB, double-buffered chunk
    __shared__ unsigned short best_lds[4][32];
    __shared__ unsigned short hist_lds[4][NQ][32];

    const int tid = threadIdx.x;
    const int w   = tid >> 6;
    const int l   = tid & 63;
    const int c   = l & 15;
    const int g   = l >> 4;

    const int blk = blockIdx.x;        // 512 blocks
    const int b   = blk >> 5;          // 32 blocks per batch element
    const int t0  = (blk & 31) * 128;
    const int tw  = t0 + w * 32;

    // per-lane DMA source base: wave w stages bytes [w*8K, w*8K+8K) of each 32 KB chunk
    const char* gsrc0 = (const char*)pks + w * 8192 + (l << 4);

    auto issue_chunk = [&](int cc, int bu) {
        cc &= 255;
        const char* src = gsrc0 + (size_t)cc * 32768;
        char* dst = (char*)(&btile[bu][0][0][0]) + w * 8192;
        #pragma unroll
        for (int i = 0; i < 8; ++i) {
            __builtin_amdgcn_global_load_lds(
                (const __attribute__((address_space(1))) unsigned int*)(src + i * 1024),
                (__attribute__((address_space(3))) unsigned int*)(dst + i * 1024),
                16, 0, 0);
        }
    };

    issue_chunk(0, 0);   // prefetch chunk 0 under the A-init loads

    // ---- A init: residual = x, split to hi/lo MFMA fragments (m-inner: line locality) ----
    bfrag ah[2][8], al[2][8];
    {
        const float* xb = x + (size_t)b * DD * TT;
        #pragma unroll
        for (int s = 0; s < 8; ++s) {
            #pragma unroll
            for (int j = 0; j < 8; ++j) {
                int d = s * 32 + g * 8 + j;
                #pragma unroll
                for (int m = 0; m < 2; ++m) {
                    int t = tw + m * 16 + c;
                    float v = xb[(size_t)d * TT + t];
                    unsigned short h = f2bf(v);
                    float rem = v - bfh2f(h);
                    ah[m][s][j] = (short)h;
                    al[m][s][j] = (short)f2bf(rem);
                }
            }
        }
    }
    __syncthreads();   // drains vmcnt -> chunk 0 resident

    // per-slot top-2 state: slot (m, j) = token m*16 + 4*g + j
    float s1[2][4], s2[2][4];
    int   i1[2][4], i2[2][4];

    auto reset_slots = [&]() {
        #pragma unroll
        for (int m = 0; m < 2; ++m)
            #pragma unroll
            for (int j = 0; j < 4; ++j) {
                s1[m][j] = -1e30f; s2[m][j] = -1e30f;
                i1[m][j] = 0x7fffffff; i2[m][j] = 0x7fffffff;
            }
    };

    // chunk compute: ds_reads pipelined one k-slice ahead of the MFMA cluster,
    // so the LDS pipe (next slice) overlaps the matrix pipe (current slice).
    auto compute_chunk = [&](int bu, int qq, int ch) {
        facc a00 = {0.f,0.f,0.f,0.f}, a01 = {0.f,0.f,0.f,0.f};
        facc a10 = {0.f,0.f,0.f,0.f}, a11 = {0.f,0.f,0.f,0.f};
        const int roff = g * 128 + c * 8;
        const float* hq = hesq + qq * BINS + ch * 32;
        float q0 = hq[c], q1 = hq[16 + c];
        const short (*bt)[16][512] = btile[bu];

        bfrag bhA0 = *(const bfrag*)&bt[0][0][roff];
        bfrag bhA1 = *(const bfrag*)&bt[0][8][roff];
        bfrag blA0 = *(const bfrag*)&bt[1][0][roff];
        bfrag blA1 = *(const bfrag*)&bt[1][8][roff];

        __builtin_amdgcn_s_setprio(1);
        #pragma unroll
        for (int s = 0; s < 8; s += 2) {
            // issue slice s+1 reads (LDS pipe works while MFMAs below run)
            bfrag bhB0 = *(const bfrag*)&bt[0][s + 1][roff];
            bfrag bhB1 = *(const bfrag*)&bt[0][s + 9][roff];
            bfrag blB0 = *(const bfrag*)&bt[1][s + 1][roff];
            bfrag blB1 = *(const bfrag*)&bt[1][s + 9][roff];
            // slice s MFMAs (A set)
            a00 = MFMA(ah[0][s], bhA0, a00);
            a10 = MFMA(ah[1][s], bhA0, a10);
            a01 = MFMA(ah[0][s], bhA1, a01);
            a11 = MFMA(ah[1][s], bhA1, a11);
            a00 = MFMA(al[0][s], bhA0, a00);
            a10 = MFMA(al[1][s], bhA0, a10);
            a01 = MFMA(al[0][s], bhA1, a01);
            a11 = MFMA(al[1][s], bhA1, a11);
            a00 = MFMA(ah[0][s], blA0, a00);
            a10 = MFMA(ah[1][s], blA0, a10);
            a01 = MFMA(ah[0][s], blA1, a01);
            a11 = MFMA(ah[1][s], blA1, a11);
            if (s < 6) {
                // issue slice s+2 reads into the A set
                bhA0 = *(const bfrag*)&bt[0][s + 2][roff];
                bhA1 = *(const bfrag*)&bt[0][s + 10][roff];
                blA0 = *(const bfrag*)&bt[1][s + 2][roff];
                blA1 = *(const bfrag*)&bt[1][s + 10][roff];
            }
            // slice s+1 MFMAs (B set)
            a00 = MFMA(ah[0][s + 1], bhB0, a00);
            a10 = MFMA(ah[1][s + 1], bhB0, a10);
            a01 = MFMA(ah[0][s + 1], bhB1, a01);
            a11 = MFMA(ah[1][s + 1], bhB1, a11);
            a00 = MFMA(al[0][s + 1], bhB0, a00);
            a10 = MFMA(al[1][s + 1], bhB0, a10);
            a01 = MFMA(al[0][s + 1], bhB1, a01);
            a11 = MFMA(al[1][s + 1], bhB1, a11);
            a00 = MFMA(ah[0][s + 1], blB0, a00);
            a10 = MFMA(ah[1][s + 1], blB0, a10);
            a01 = MFMA(ah[0][s + 1], blB1, a01);
            a11 = MFMA(ah[1][s + 1], blB1, a11);
        }
        __builtin_amdgcn_s_setprio(0);

        int bin0 = ch * 32 + c;
        #pragma unroll
        for (int j = 0; j < 4; ++j) {
            float v;
            v = a00[j] - q0; UPD2(v, bin0,      s1[0][j], i1[0][j], s2[0][j], i2[0][j]);
            v = a01[j] - q1; UPD2(v, bin0 + 16, s1[0][j], i1[0][j], s2[0][j], i2[0][j]);
            v = a10[j] - q0; UPD2(v, bin0,      s1[1][j], i1[1][j], s2[1][j], i2[1][j]);
            v = a11[j] - q1; UPD2(v, bin0 + 16, s1[1][j], i1[1][j], s2[1][j], i2[1][j]);
        }
    };

    auto stage_end = [&](int qq) {
        // cross-lane top-2 merge over the 16 column lanes
        #pragma unroll
        for (int m = 0; m < 2; ++m)
            #pragma unroll
            for (int j = 0; j < 4; ++j) {
                float a1 = s1[m][j], a2 = s2[m][j];
                int   x1 = i1[m][j], x2 = i2[m][j];
                #pragma unroll
                for (int mk = 1; mk < 16; mk <<= 1) {
                    float b1 = __shfl_xor(a1, mk), b2 = __shfl_xor(a2, mk);
                    int   y1 = __shfl_xor(x1, mk), y2 = __shfl_xor(x2, mk);
                    bool bG = (b1 > a1) || (b1 == a1 && y1 < x1);
                    float w1 = bG ? b1 : a1; int wi1 = bG ? y1 : x1;
                    float ls = bG ? a1 : b1; int li  = bG ? x1 : y1;
                    float o2 = bG ? b2 : a2; int oi  = bG ? y2 : x2;
                    bool sG = (ls > o2) || (ls == o2 && li < oi);
                    a1 = w1; x1 = wi1;
                    a2 = sG ? ls : o2; x2 = sG ? li : oi;
                }
                s1[m][j] = a1; i1[m][j] = x1; s2[m][j] = a2; i2[m][j] = x2;
            }

        int bch[2][4];
        bool need = false;
        #pragma unroll
        for (int m = 0; m < 2; ++m)
            #pragma unroll
            for (int j = 0; j < 4; ++j) {
                bch[m][j] = i1[m][j];
                need = need || (s1[m][j] - s2[m][j] <= DELTA);
            }

        if (__any(need)) {
            // rare: exact fp32 residual chain + fp64 re-score of the two candidates
            #pragma unroll
            for (int m = 0; m < 2; ++m)
                #pragma unroll
                for (int j = 0; j < 4; ++j) {
                    unsigned long long nm = __ballot(s1[m][j] - s2[m][j] <= DELTA);
                    if (nm) {
                        for (int g2 = 0; g2 < 4; ++g2) {
                            if ((nm >> (g2 * 16)) & 1ull) {
                                int c1 = __shfl(i1[m][j], g2 * 16);
                                int c2 = __shfl(i2[m][j], g2 * 16);
                                int tkl = m * 16 + g2 * 4 + j;
                                int t = tw + tkl;
                                double p1 = 0.0, p2 = 0.0;
                                const float* e1p = cb + (size_t)(qq * BINS + c1) * DD;
                                const float* e2p = cb + (size_t)(qq * BINS + c2) * DD;
                                #pragma unroll
                                for (int dd = 0; dd < 4; ++dd) {
                                    int d = l * 4 + dd;
                                    float rv = x[((size_t)b * DD + d) * TT + t];
                                    for (int k = 0; k < qq; ++k) {
                                        int hb = hist_lds[w][k][tkl];
                                        rv -= cb[(size_t)(k * BINS + hb) * DD + d];
                                    }
                                    float e1v = e1p[d], e2v = e2p[d];
                                    p1 += (double)e1v * (2.0 * (double)rv - (double)e1v);
                                    p2 += (double)e2v * (2.0 * (double)rv - (double)e2v);
                                }
                                #pragma unroll
                                for (int mk = 1; mk < 64; mk <<= 1) {
                                    p1 += __shfl_xor(p1, mk);
                                    p2 += __shfl_xor(p2, mk);
                                }
                                int wb = (p1 > p2 || (p1 == p2 && c1 < c2)) ? c1 : c2;
                                if (g == g2) bch[m][j] = wb;
                            }
                        }
                    }
                }
        }

        // writes: codes + per-wave best/history
        if (c == 0) {
            #pragma unroll
            for (int m = 0; m < 2; ++m)
                #pragma unroll
                for (int j = 0; j < 4; ++j) {
                    int tkl = m * 16 + g * 4 + j;
                    best_lds[w][tkl] = (unsigned short)bch[m][j];
                    hist_lds[w][qq][tkl] = (unsigned short)bch[m][j];
                    out[OUTQ + ((size_t)qq * BB + b) * TT + tw + tkl] = (float)bch[m][j];
                }
        }

        // residual update from EXACT fp32 codebook row: r -= e[best], re-split hi/lo
        #pragma unroll
        for (int m = 0; m < 2; ++m) {
            int bin = best_lds[w][m * 16 + c];
            const float* ep = cb + (size_t)(qq * BINS + bin) * DD + g * 8;
            #pragma unroll
            for (int s = 0; s < 8; ++s) {
                float4 e0 = *(const float4*)(ep + s * 32);
                float4 e1 = *(const float4*)(ep + s * 32 + 4);
                float ev[8] = { e0.x, e0.y, e0.z, e0.w, e1.x, e1.y, e1.z, e1.w };
                #pragma unroll
                for (int j = 0; j < 8; ++j) {
                    float rv = bfh2f((unsigned short)ah[m][s][j]) + bfh2f((unsigned short)al[m][s][j]);
                    float nr = rv - ev[j];
                    unsigned short nh = f2bf(nr);
                    float rem = nr - bfh2f(nh);
                    ah[m][s][j] = (short)nh;
                    al[m][s][j] = (short)f2bf(rem);
                }
            }
        }
    };

    // ---- main loop: 8 stages x 32 chunks, 2-phase (issue-next / compute / barrier) ----
    int buf = 0;
    for (int q = 0; q < NQ; ++q) {
        reset_slots();
        for (int ch = 0; ch < 32; ++ch) {
            issue_chunk(q * 32 + ch + 1, buf ^ 1);
            compute_chunk(buf, q, ch);
            if (ch == 31) stage_end(q);
            __syncthreads();           // drains vmcnt(0): next chunk's DMA resident
            buf ^= 1;
        }
    }

    // ---- final: quantized = x - residual (m-inner: full 128B line back-to-back) ----
    {
        const float* xb = x + (size_t)b * DD * TT;
        float* ob = out + (size_t)b * DD * TT;
        #pragma unroll
        for (int s = 0; s < 8; ++s)
            #pragma unroll
            for (int j = 0; j < 8; ++j) {
                int d = s * 32 + g * 8 + j;
                #pragma unroll
                for (int m = 0; m < 2; ++m) {
                    int t = tw + m * 16 + c;
                    float rv = bfh2f((unsigned short)ah[m][s][j]) + bfh2f((unsigned short)al[m][s][j]);
                    ob[(size_t)d * TT + t] = xb[(size_t)d * TT + t] - rv;
                }
            }
    }
}

// ================= fallback fp32 path (round-2, known-good) =================
#define TOK_PER_BLK 32
#define BIN_CHUNK   128
#define KC          32
#define EPAD        36
#define RPAD        260

#define FUPD2(S, BIN, B1, I1, B2, I2)                                        \
    if ((S) > (B2) || ((S) == (B2) && (BIN) < (I2))) {                      \
        if ((S) > (B1) || ((S) == (B1) && (BIN) < (I1))) {                  \
            B2 = B1; I2 = I1; B1 = (S); I1 = (BIN);                         \
        } else { B2 = (S); I2 = (BIN); }                                    \
    }

__global__ __launch_bounds__(256, 2)
void rvq_esq_kernel(const float* __restrict__ cb, float* __restrict__ esq) {
    int q = blockIdx.x;
    const float* e = cb + (size_t)q * BINS * DD;
    for (int bin = threadIdx.x; bin < BINS; bin += 256) {
        const float4* row = (const float4*)(e + (size_t)bin * DD);
        float s = 0.f;
        #pragma unroll 8
        for (int i = 0; i < DD / 4; ++i) {
            float4 v = row[i];
            s += v.x * v.x + v.y * v.y + v.z * v.z + v.w * v.w;
        }
        esq[q * BINS + bin] = s;
    }
}

__global__ __launch_bounds__(256, 2)
void rvq_main_kernel(const float* __restrict__ x, const float* __restrict__ cb,
                     const float* __restrict__ esq, float* __restrict__ out) {
    __shared__ float r_lds[TOK_PER_BLK][RPAD];
    __shared__ float e_lds[BIN_CHUNK][EPAD];
    __shared__ float red_s[16][2][TOK_PER_BLK];
    __shared__ int   red_i[16][2][TOK_PER_BLK];
    __shared__ int   best_lds2[TOK_PER_BLK];

    const int tid = threadIdx.x;
    const int blk = blockIdx.x;
    const int b   = blk >> 7;
    const int t0  = (blk & 127) * TOK_PER_BLK;

    {
        const int tl = tid & 31;
        const int d0 = (tid >> 5) * 32;
        const float* xp = x + (size_t)b * DD * TT + t0 + tl;
        for (int dd = 0; dd < 32; ++dd) {
            int d = d0 + dd;
            r_lds[tl][d] = xp[(size_t)d * TT];
        }
    }
    __syncthreads();

    const int ty = tid >> 4;
    const int tx = tid & 15;

    for (int q = 0; q < NQ; ++q) {
        const float* eb = cb + (size_t)q * BINS * DD;
        const float* es = esq + q * BINS;
        float b1[2] = {-1e30f, -1e30f}, b2[2] = {-1e30f, -1e30f};
        int   i1[2] = {0x7fffffff, 0x7fffffff}, i2[2] = {0x7fffffff, 0x7fffffff};

        for (int cch = 0; cch < BINS / BIN_CHUNK; ++cch) {
            float acc[2][8];
            #pragma unroll
            for (int i = 0; i < 2; ++i)
                #pragma unroll
                for (int j = 0; j < 8; ++j) acc[i][j] = 0.f;

            for (int kc = 0; kc < DD / KC; ++kc) {
                __syncthreads();
                {
                    const int col  = tid & 7;
                    const int row0 = tid >> 3;
                    const float* src = eb + (size_t)(cch * BIN_CHUNK) * DD + kc * KC;
                    #pragma unroll
                    for (int rr = 0; rr < 4; ++rr) {
                        int row = row0 + rr * 32;
                        float4 v = *(const float4*)(src + (size_t)row * DD + col * 4);
                        *(float4*)&e_lds[row][col * 4] = v;
                    }
                }
                __syncthreads();
                #pragma unroll
                for (int k4 = 0; k4 < KC / 4; ++k4) {
                    float4 r0 = *(const float4*)&r_lds[tx][kc * KC + k4 * 4];
                    float4 r1 = *(const float4*)&r_lds[tx + 16][kc * KC + k4 * 4];
                    #pragma unroll
                    for (int bi = 0; bi < 8; ++bi) {
                        float4 e4 = *(const float4*)&e_lds[ty + 16 * bi][k4 * 4];
                        acc[0][bi] += r0.x * e4.x + r0.y * e4.y + r0.z * e4.z + r0.w * e4.w;
                        acc[1][bi] += r1.x * e4.x + r1.y * e4.y + r1.z * e4.z + r1.w * e4.w;
                    }
                }
            }
            #pragma unroll
            for (int bi = 0; bi < 8; ++bi) {
                int bin = cch * BIN_CHUNK + ty + 16 * bi;
                float half_esq = 0.5f * es[bin];
                float s0 = acc[0][bi] - half_esq;
                float s1v = acc[1][bi] - half_esq;
                FUPD2(s0, bin, b1[0], i1[0], b2[0], i2[0]);
                FUPD2(s1v, bin, b1[1], i1[1], b2[1], i2[1]);
            }
        }

        #pragma unroll
        for (int k = 0; k < 2; ++k) {
            red_s[ty][k][tx]      = k ? b2[0] : b1[0];
            red_i[ty][k][tx]      = k ? i2[0] : i1[0];
            red_s[ty][k][tx + 16] = k ? b2[1] : b1[1];
            red_i[ty][k][tx + 16] = k ? i2[1] : i1[1];
        }
        __syncthreads();

        if (tid < TOK_PER_BLK) {
            float g1 = -1e30f, g2 = -1e30f; int gi1 = 0x7fffffff, gi2 = 0x7fffffff;
            #pragma unroll
            for (int j = 0; j < 16; ++j) {
                #pragma unroll
                for (int k = 0; k < 2; ++k) {
                    float s = red_s[j][k][tid]; int ii = red_i[j][k][tid];
                    FUPD2(s, ii, g1, gi1, g2, gi2);
                }
            }
            int bif;
            if (g1 - g2 <= DELTA) {
                const float* rrow = r_lds[tid];
                double sc[2]; int id2[2] = { gi1, gi2 };
                for (int cc2 = 0; cc2 < 2; ++cc2) {
                    const float* ep = eb + (size_t)id2[cc2] * DD;
                    double acc2 = 0.0;
                    #pragma unroll 4
                    for (int d = 0; d < DD; ++d) {
                        double ev = (double)ep[d];
                        acc2 += ev * (2.0 * (double)rrow[d] - ev);
                    }
                    sc[cc2] = acc2;
                }
                bif = (sc[0] > sc[1] || (sc[0] == sc[1] && id2[0] < id2[1])) ? id2[0] : id2[1];
            } else {
                bif = gi1;
            }
            best_lds2[tid] = bif;
            out[OUTQ + (size_t)q * (BB * TT) + (size_t)b * TT + t0 + tid] = (float)bif;
        }
        __syncthreads();

        {
            const int tok  = tid >> 3;
            const int part = tid & 7;
            const int bin  = best_lds2[tok];
            const float* ep = eb + (size_t)bin * DD + part * 32;
            float* rp = &r_lds[tok][part * 32];
            #pragma unroll
            for (int dd = 0; dd < 32; ++dd) rp[dd] -= ep[dd];
        }
        __syncthreads();
    }

    {
        const int tl = tid & 31;
        const int d0 = (tid >> 5) * 32;
        const float* xp = x + (size_t)b * DD * TT + t0 + tl;
        float*       op = out + (size_t)b * DD * TT + t0 + tl;
        for (int dd = 0; dd < 32; ++dd) {
            int d = d0 + dd;
            op[(size_t)d * TT] = xp[(size_t)d * TT] - r_lds[tl][d];
        }
    }
}

extern "C" void kernel_launch(void* const* d_in, const int* in_sizes, int n_in,
                              void* d_out, int out_size, void* d_ws, size_t ws_size,
                              hipStream_t stream) {
    const float* x  = (const float*)d_in[0];
    const float* cb = (const float*)d_in[1];
    float* out = (float*)d_out;

    const size_t PKS_BYTES = (size_t)NQ * BINS * DD * 2 * 2;   // 8 MB pre-swizzled hi/lo
    const size_t NEED = PKS_BYTES + (size_t)NQ * BINS * 4;     // + half-esq

    if (ws_size >= NEED) {
        unsigned short* pks = (unsigned short*)d_ws;
        float* hesq = (float*)((char*)d_ws + PKS_BYTES);
        rvq_pack_swz<<<(NQ * BINS * 8) / 256, 256, 0, stream>>>(cb, pks);
        rvq_esq_half<<<NQ, 256, 0, stream>>>(cb, hesq);
        rvq_mfma2_kernel<<<512, 256, 0, stream>>>(x, cb, pks, hesq, out);
    } else {
        float* esq = (float*)d_ws;
        rvq_esq_kernel<<<NQ, 256, 0, stream>>>(cb, esq);
        rvq_main_kernel<<<(BB * TT) / TOK_PER_BLK, 256, 0, stream>>>(x, cb, esq, out);
    }
}